// Round 1
// baseline (654.214 us; speedup 1.0000x reference)
//
#include <hip/hip_runtime.h>

#define HD 257
#define WD 257
#define CIN 16
#define COUT 64
#define NK 9
// S = B*HD*WD = 8*257*257 = 528392 cells

__global__ void zero_ws_kernel(float* __restrict__ ws, int n) {
    int i = blockIdx.x * blockDim.x + threadIdx.x;
    int stride = gridDim.x * blockDim.x;
    for (; i < n; i += stride) ws[i] = 0.0f;
}

__global__ void scatter_kernel(const float* __restrict__ xyzp,
                               const float* __restrict__ feat,
                               float* __restrict__ vox,   // [S][16] sums
                               float* __restrict__ cnt,   // [S]
                               int BN, int logN) {
    int p = blockIdx.x * blockDim.x + threadIdx.x;
    if (p >= BN) return;
    int b = p >> logN;
    float4 v = reinterpret_cast<const float4*>(xyzp)[p];
    float ry = fminf(fmaxf(rintf(v.y * 256.0f), 0.0f), 256.0f);
    float rx = fminf(fmaxf(rintf(v.x * 256.0f), 0.0f), 256.0f);
    int y = (int)ry, x = (int)rx;
    int cell = (b * HD + y) * WD + x;
    float* dst = vox + (size_t)cell * CIN;
    float pc = v.w;
    atomicAdd(&dst[0], pc);
    atomicAdd(&dst[1], 1.0f - pc);
    const float* f = feat + (size_t)p * 14;
#pragma unroll
    for (int c = 0; c < 14; ++c) atomicAdd(&dst[2 + c], f[c]);
    atomicAdd(&cnt[cell], 1.0f);
}

__global__ void normalize_kernel(float* __restrict__ vox,
                                 const float* __restrict__ cnt, int total) {
    int i = blockIdx.x * blockDim.x + threadIdx.x;
    int stride = gridDim.x * blockDim.x;
    for (; i < total; i += stride) {
        int cell = i >> 4;  // CIN=16
        float c = fmaxf(cnt[cell], 1.0f);
        vox[i] = vox[i] / c;
    }
}

__global__ __launch_bounds__(256) void gather_mm_kernel(
    const float* __restrict__ xyzp,
    const float* __restrict__ vox,   // [S][16] means
    const float* __restrict__ W,     // [9][16][64]
    const float* __restrict__ bias,  // [64]
    float* __restrict__ out,         // [BN][64]
    int logN) {
    __shared__ float sW[NK * CIN * COUT];  // 36 KB
    int tid = threadIdx.x;
#pragma unroll
    for (int i = tid; i < NK * CIN * COUT; i += 256) sW[i] = W[i];
    __syncthreads();

    int lane = tid & 63;
    int grp  = tid >> 6;            // wave index within block; wave-uniform point
    int p = blockIdx.x * 4 + grp;
    int b = p >> logN;

    float4 v = reinterpret_cast<const float4*>(xyzp)[p];
    int y = (int)fminf(fmaxf(rintf(v.y * 256.0f), 0.0f), 256.0f);
    int x = (int)fminf(fmaxf(rintf(v.x * 256.0f), 0.0f), 256.0f);

    float acc = bias[lane];
#pragma unroll
    for (int dy = -1; dy <= 1; ++dy) {
#pragma unroll
        for (int dx = -1; dx <= 1; ++dx) {
            int k = (dy + 1) * 3 + (dx + 1);
            int ny = y + dy, nx = x + dx;
            if (ny < 0 || ny >= HD || nx < 0 || nx >= WD) continue;  // wave-uniform
            const float* vc = vox + ((size_t)((b * HD + ny) * WD + nx)) * CIN;
            const float* wk = sW + k * CIN * COUT + lane;
#pragma unroll
            for (int c = 0; c < CIN; ++c) {
                acc = fmaf(vc[c], wk[c * COUT], acc);
            }
        }
    }
    out[(size_t)p * COUT + lane] = acc;
}

extern "C" void kernel_launch(void* const* d_in, const int* in_sizes, int n_in,
                              void* d_out, int out_size, void* d_ws, size_t ws_size,
                              hipStream_t stream) {
    const float* xyzp = (const float*)d_in[0];   // (B,N,4)
    const float* feat = (const float*)d_in[1];   // (B,N,14)
    const float* W    = (const float*)d_in[2];   // (9,16,64)
    const float* bias = (const float*)d_in[3];   // (64,)
    float* out = (float*)d_out;

    const int BN = in_sizes[0] / 4;              // 262144
    const int B  = 8;
    const int N  = BN / B;                       // 32768
    int logN = 0;
    while ((1 << logN) < N) ++logN;              // 15

    const int S = B * HD * WD;                   // 528392
    float* vox = (float*)d_ws;                   // S*16 floats
    float* cnt = vox + (size_t)S * CIN;          // S floats
    (void)ws_size;

    // 1. zero accumulators (must re-zero every call — graph replays)
    int zn = S * (CIN + 1);
    zero_ws_kernel<<<2048, 256, 0, stream>>>((float*)d_ws, zn);

    // 2. scatter-add features + counts
    scatter_kernel<<<(BN + 255) / 256, 256, 0, stream>>>(xyzp, feat, vox, cnt, BN, logN);

    // 3. sums -> means
    normalize_kernel<<<2048, 256, 0, stream>>>(vox, cnt, S * CIN);

    // 4. gather 3x3 neighborhood + per-point GEMV
    gather_mm_kernel<<<BN / 4, 256, 0, stream>>>(xyzp, vox, W, bias, out, logN);
}

// Round 2
// 516.768 us; speedup vs baseline: 1.2660x; 1.2660x over previous
//
#include <hip/hip_runtime.h>

#define HD 257
#define WD 257
#define CIN 16
#define COUT 64
#define NK 9
#define PPW 8    // points per wave
#define WAVES 4  // waves per block
// S = B*HD*WD = 8*257*257 = 528392 cells; vox = [S][16] f32 sums (33.8 MB)

__global__ void scatter_kernel(const float* __restrict__ xyzp,
                               const float* __restrict__ feat,
                               float* __restrict__ vox,
                               int BN, int logN) {
    int p = blockIdx.x * blockDim.x + threadIdx.x;
    if (p >= BN) return;
    int b = p >> logN;
    float4 v = reinterpret_cast<const float4*>(xyzp)[p];
    int y = (int)fminf(fmaxf(rintf(v.y * 256.0f), 0.0f), 256.0f);
    int x = (int)fminf(fmaxf(rintf(v.x * 256.0f), 0.0f), 256.0f);
    int cell = (b * HD + y) * WD + x;
    float* dst = vox + (size_t)cell * CIN;
    // ch0+ch1 sums to exactly one "count" per point: p + (1-p)
    atomicAdd(&dst[0], v.w);
    atomicAdd(&dst[1], 1.0f - v.w);
    const float2* f2 = reinterpret_cast<const float2*>(feat + (size_t)p * 14);
#pragma unroll
    for (int c = 0; c < 7; ++c) {
        float2 fv = f2[c];
        atomicAdd(&dst[2 + 2 * c], fv.x);
        atomicAdd(&dst[3 + 2 * c], fv.y);
    }
}

__global__ __launch_bounds__(256) void gather_mm_kernel(
    const float* __restrict__ xyzp,
    const float* __restrict__ vox,   // [S][16] raw sums; count = row[0]+row[1]
    const float* __restrict__ W,     // [9][16][64]
    const float* __restrict__ bias,  // [64]
    float* __restrict__ out,         // [BN][64]
    int logN) {
    __shared__ float sW[NK * CIN * COUT];  // 36 KB -> 4 blocks/CU (LDS-limited)
    int tid = threadIdx.x;
    {
        const float4* W4 = reinterpret_cast<const float4*>(W);
        float4* sW4 = reinterpret_cast<float4*>(sW);
#pragma unroll
        for (int i = tid; i < NK * CIN * COUT / 4; i += 256) sW4[i] = W4[i];
    }
    __syncthreads();

    int lane = tid & 63;
    int wid = tid >> 6;
    int p0 = (blockIdx.x * WAVES + wid) * PPW;  // wave-uniform

    int yy[PPW], xx[PPW], bb[PPW];
    float acc[PPW];
    float bv = bias[lane];
#pragma unroll
    for (int i = 0; i < PPW; ++i) {
        float4 v = reinterpret_cast<const float4*>(xyzp)[p0 + i];
        yy[i] = (int)fminf(fmaxf(rintf(v.y * 256.0f), 0.0f), 256.0f);
        xx[i] = (int)fminf(fmaxf(rintf(v.x * 256.0f), 0.0f), 256.0f);
        bb[i] = (p0 + i) >> logN;
        acc[i] = bv;
    }

#pragma unroll
    for (int dy = -1; dy <= 1; ++dy) {
#pragma unroll
        for (int dx = -1; dx <= 1; ++dx) {
            const int k = (dy + 1) * 3 + (dx + 1);
            float w[CIN];
#pragma unroll
            for (int c = 0; c < CIN; ++c)
                w[c] = sW[(k * CIN + c) * COUT + lane];  // stride-1/lane: conflict-free
#pragma unroll
            for (int i = 0; i < PPW; ++i) {
                int ny = yy[i] + dy, nx = xx[i] + dx;
                if (ny < 0 || ny > 256 || nx < 0 || nx > 256) continue;  // wave-uniform
                const float4* row = reinterpret_cast<const float4*>(
                    vox + ((size_t)((bb[i] * HD + ny) * WD + nx)) * CIN);
                float4 r0 = row[0], r1 = row[1], r2 = row[2], r3 = row[3];
                float cntv = r0.x + r0.y;  // == count (each point adds p + (1-p))
                float inv = __builtin_amdgcn_rcpf(fmaxf(cntv, 1.0f));
                float t;
                t = r0.x * w[0];
                t = fmaf(r0.y, w[1], t);
                t = fmaf(r0.z, w[2], t);
                t = fmaf(r0.w, w[3], t);
                t = fmaf(r1.x, w[4], t);
                t = fmaf(r1.y, w[5], t);
                t = fmaf(r1.z, w[6], t);
                t = fmaf(r1.w, w[7], t);
                t = fmaf(r2.x, w[8], t);
                t = fmaf(r2.y, w[9], t);
                t = fmaf(r2.z, w[10], t);
                t = fmaf(r2.w, w[11], t);
                t = fmaf(r3.x, w[12], t);
                t = fmaf(r3.y, w[13], t);
                t = fmaf(r3.z, w[14], t);
                t = fmaf(r3.w, w[15], t);
                acc[i] = fmaf(t, inv, acc[i]);
            }
        }
    }
#pragma unroll
    for (int i = 0; i < PPW; ++i)
        out[(size_t)(p0 + i) * COUT + lane] = acc[i];
}

extern "C" void kernel_launch(void* const* d_in, const int* in_sizes, int n_in,
                              void* d_out, int out_size, void* d_ws, size_t ws_size,
                              hipStream_t stream) {
    const float* xyzp = (const float*)d_in[0];   // (B,N,4)
    const float* feat = (const float*)d_in[1];   // (B,N,14)
    const float* W    = (const float*)d_in[2];   // (9,16,64)
    const float* bias = (const float*)d_in[3];   // (64,)
    float* out = (float*)d_out;

    const int BN = in_sizes[0] / 4;  // 262144
    const int B = 8;
    const int N = BN / B;            // 32768
    int logN = 0;
    while ((1 << logN) < N) ++logN;  // 15

    const int S = B * HD * WD;       // 528392
    float* vox = (float*)d_ws;       // S*16 floats = 33.8 MB
    (void)ws_size;

    // 1. zero accumulators (graph replays -> must re-zero every call)
    hipMemsetAsync(vox, 0, (size_t)S * CIN * sizeof(float), stream);

    // 2. scatter-add features (count is implicit in ch0+ch1)
    scatter_kernel<<<(BN + 255) / 256, 256, 0, stream>>>(xyzp, feat, vox, BN, logN);

    // 3. gather 3x3 + per-point GEMV, normalization fused (count from row, rcp)
    gather_mm_kernel<<<BN / (WAVES * PPW), 256, 0, stream>>>(xyzp, vox, W, bias, out, logN);
}

// Round 3
// 260.705 us; speedup vs baseline: 2.5094x; 1.9822x over previous
//
#include <hip/hip_runtime.h>

#define HD 257
#define WD 257
#define NK 9
#define COUT 64
#define PPW 8    // points per wave
#define WAVES 4  // waves per block

typedef unsigned int uint;

// f32 -> bf16 RNE pack (a -> low16, b -> high16)
__device__ __forceinline__ uint pack_bf16(float a, float b) {
    uint ua = __float_as_uint(a), ub = __float_as_uint(b);
    ua += 0x7fffu + ((ua >> 16) & 1u);
    ub += 0x7fffu + ((ub >> 16) & 1u);
    return (ua >> 16) | (ub & 0xffff0000u);
}

// packed 2xbf16 atomic add, device scope (sc1) — atomics may come from any XCD
__device__ __forceinline__ void atomic_pk_add_bf16(uint* addr, uint val) {
    asm volatile("global_atomic_pk_add_bf16 %0, %1, off sc1"
                 :: "v"(addr), "v"(val) : "memory");
}

__global__ void scatter_kernel(const float* __restrict__ xyzp,
                               const float* __restrict__ feat,
                               uint* __restrict__ voxb,  // [S][8] packed bf16 pairs
                               int BN, int logN) {
    int p = blockIdx.x * blockDim.x + threadIdx.x;
    if (p >= BN) return;
    int b = p >> logN;
    float4 v = reinterpret_cast<const float4*>(xyzp)[p];
    int y = (int)fminf(fmaxf(rintf(v.y * 256.0f), 0.0f), 256.0f);
    int x = (int)fminf(fmaxf(rintf(v.x * 256.0f), 0.0f), 256.0f);
    uint* dst = voxb + (size_t)((b * HD + y) * WD + x) * 8;
    const float2* f2 = reinterpret_cast<const float2*>(feat + (size_t)p * 14);
    float2 f0 = f2[0], f1 = f2[1], f2v = f2[2], f3 = f2[3];
    float2 f4 = f2[4], f5 = f2[5], f6 = f2[6];
    atomic_pk_add_bf16(dst + 0, pack_bf16(v.w, 1.0f - v.w));
    atomic_pk_add_bf16(dst + 1, pack_bf16(f0.x, f0.y));
    atomic_pk_add_bf16(dst + 2, pack_bf16(f1.x, f1.y));
    atomic_pk_add_bf16(dst + 3, pack_bf16(f2v.x, f2v.y));
    atomic_pk_add_bf16(dst + 4, pack_bf16(f3.x, f3.y));
    atomic_pk_add_bf16(dst + 5, pack_bf16(f4.x, f4.y));
    atomic_pk_add_bf16(dst + 6, pack_bf16(f5.x, f5.y));
    atomic_pk_add_bf16(dst + 7, pack_bf16(f6.x, f6.y));
}

// bf16 sums -> normalized f32 rows. count = ch0+ch1 (each point adds p + (1-p)).
__global__ void repack_kernel(const uint* __restrict__ vin,
                              float* __restrict__ vout, int S) {
    int c = blockIdx.x * blockDim.x + threadIdx.x;
    if (c >= S) return;
    const uint4* rp = reinterpret_cast<const uint4*>(vin) + (size_t)c * 2;
    uint4 a = rp[0], b = rp[1];
    float f[16];
    uint d[8] = {a.x, a.y, a.z, a.w, b.x, b.y, b.z, b.w};
#pragma unroll
    for (int j = 0; j < 8; ++j) {
        f[2 * j]     = __uint_as_float(d[j] << 16);
        f[2 * j + 1] = __uint_as_float(d[j] & 0xffff0000u);
    }
    float inv = __builtin_amdgcn_rcpf(fmaxf(f[0] + f[1], 1.0f));
    float4* o = reinterpret_cast<float4*>(vout + (size_t)c * 16);
    o[0] = make_float4(f[0] * inv, f[1] * inv, f[2] * inv, f[3] * inv);
    o[1] = make_float4(f[4] * inv, f[5] * inv, f[6] * inv, f[7] * inv);
    o[2] = make_float4(f[8] * inv, f[9] * inv, f[10] * inv, f[11] * inv);
    o[3] = make_float4(f[12] * inv, f[13] * inv, f[14] * inv, f[15] * inv);
}

template <bool F32>
__global__ __launch_bounds__(256, 8) void gather_kernel(
    const float* __restrict__ xyzp,
    const float* __restrict__ voxn,  // F32 path: [S][16] normalized means
    const uint* __restrict__ voxb,   // fallback: [S][8] raw bf16 sums
    const float* __restrict__ W,     // [9][16][64] f32
    const float* __restrict__ bias,
    float* __restrict__ out, int logN) {
    __shared__ uint sW[NK * 8 * 64];  // bf16-packed: 18 KB -> 8 blocks/CU
    for (int idx = threadIdx.x; idx < NK * 8 * 64; idx += 256) {
        int k = idx >> 9;
        int r = idx & 511;
        int cp = r >> 6, d = r & 63;
        float lo = W[(k * 16 + 2 * cp) * 64 + d];
        float hi = W[(k * 16 + 2 * cp + 1) * 64 + d];
        sW[idx] = pack_bf16(lo, hi);
    }
    __syncthreads();

    int lane = threadIdx.x & 63, wid = threadIdx.x >> 6;
    int p0 = (blockIdx.x * WAVES + wid) * PPW;

    int sy[PPW], sx[PPW], sc[PPW];
    float acc[PPW];
    float bv = bias[lane];
#pragma unroll
    for (int i = 0; i < PPW; ++i) {
        float4 v = reinterpret_cast<const float4*>(xyzp)[p0 + i];
        int y = (int)fminf(fmaxf(rintf(v.y * 256.0f), 0.0f), 256.0f);
        int x = (int)fminf(fmaxf(rintf(v.x * 256.0f), 0.0f), 256.0f);
        int cell = (((p0 + i) >> logN) * HD + y) * WD + x;
        sy[i] = __builtin_amdgcn_readfirstlane(y);   // wave-uniform -> SGPR
        sx[i] = __builtin_amdgcn_readfirstlane(x);
        sc[i] = __builtin_amdgcn_readfirstlane(cell);
        acc[i] = bv;
    }

#pragma unroll
    for (int dy = -1; dy <= 1; ++dy) {
#pragma unroll
        for (int dx = -1; dx <= 1; ++dx) {
            const int k = (dy + 1) * 3 + (dx + 1);
            float wf[16];
#pragma unroll
            for (int j = 0; j < 8; ++j) {
                uint wp = sW[(k * 8 + j) * 64 + lane];  // stride-1/lane: conflict-free
                wf[2 * j]     = __uint_as_float(wp << 16);
                wf[2 * j + 1] = __uint_as_float(wp & 0xffff0000u);
            }
#pragma unroll
            for (int i = 0; i < PPW; ++i) {
                int ny = sy[i] + dy, nx = sx[i] + dx;
                if ((unsigned)ny > 256u || (unsigned)nx > 256u) continue;  // uniform
                int nc = sc[i] + dy * WD + dx;
                if (F32) {
                    const float* r = voxn + (size_t)nc * 16;  // uniform -> s_load
                    acc[i] = fmaf(r[0], wf[0], acc[i]);
                    acc[i] = fmaf(r[1], wf[1], acc[i]);
                    acc[i] = fmaf(r[2], wf[2], acc[i]);
                    acc[i] = fmaf(r[3], wf[3], acc[i]);
                    acc[i] = fmaf(r[4], wf[4], acc[i]);
                    acc[i] = fmaf(r[5], wf[5], acc[i]);
                    acc[i] = fmaf(r[6], wf[6], acc[i]);
                    acc[i] = fmaf(r[7], wf[7], acc[i]);
                    acc[i] = fmaf(r[8], wf[8], acc[i]);
                    acc[i] = fmaf(r[9], wf[9], acc[i]);
                    acc[i] = fmaf(r[10], wf[10], acc[i]);
                    acc[i] = fmaf(r[11], wf[11], acc[i]);
                    acc[i] = fmaf(r[12], wf[12], acc[i]);
                    acc[i] = fmaf(r[13], wf[13], acc[i]);
                    acc[i] = fmaf(r[14], wf[14], acc[i]);
                    acc[i] = fmaf(r[15], wf[15], acc[i]);
                } else {
                    const uint* r = voxb + (size_t)nc * 8;
                    uint d0 = r[0], d1 = r[1], d2 = r[2], d3 = r[3];
                    uint d4 = r[4], d5 = r[5], d6 = r[6], d7 = r[7];
                    float c0 = __uint_as_float(d0 << 16);
                    float c1 = __uint_as_float(d0 & 0xffff0000u);
                    float inv = __builtin_amdgcn_rcpf(fmaxf(c0 + c1, 1.0f));
                    float t;
                    t = c0 * wf[0];
                    t = fmaf(c1, wf[1], t);
                    t = fmaf(__uint_as_float(d1 << 16), wf[2], t);
                    t = fmaf(__uint_as_float(d1 & 0xffff0000u), wf[3], t);
                    t = fmaf(__uint_as_float(d2 << 16), wf[4], t);
                    t = fmaf(__uint_as_float(d2 & 0xffff0000u), wf[5], t);
                    t = fmaf(__uint_as_float(d3 << 16), wf[6], t);
                    t = fmaf(__uint_as_float(d3 & 0xffff0000u), wf[7], t);
                    t = fmaf(__uint_as_float(d4 << 16), wf[8], t);
                    t = fmaf(__uint_as_float(d4 & 0xffff0000u), wf[9], t);
                    t = fmaf(__uint_as_float(d5 << 16), wf[10], t);
                    t = fmaf(__uint_as_float(d5 & 0xffff0000u), wf[11], t);
                    t = fmaf(__uint_as_float(d6 << 16), wf[12], t);
                    t = fmaf(__uint_as_float(d6 & 0xffff0000u), wf[13], t);
                    t = fmaf(__uint_as_float(d7 << 16), wf[14], t);
                    t = fmaf(__uint_as_float(d7 & 0xffff0000u), wf[15], t);
                    acc[i] = fmaf(t, inv, acc[i]);
                }
            }
        }
    }
#pragma unroll
    for (int i = 0; i < PPW; ++i)
        out[(size_t)(p0 + i) * COUT + lane] = acc[i];
}

extern "C" void kernel_launch(void* const* d_in, const int* in_sizes, int n_in,
                              void* d_out, int out_size, void* d_ws, size_t ws_size,
                              hipStream_t stream) {
    const float* xyzp = (const float*)d_in[0];
    const float* feat = (const float*)d_in[1];
    const float* W    = (const float*)d_in[2];
    const float* bias = (const float*)d_in[3];
    float* out = (float*)d_out;

    const int BN = in_sizes[0] / 4;  // 262144
    const int B = 8;
    const int N = BN / B;
    int logN = 0;
    while ((1 << logN) < N) ++logN;  // 15

    const int S = B * HD * WD;                       // 528392
    uint* voxb = (uint*)d_ws;                        // S*8 dwords = 16.9 MB
    float* voxn = (float*)d_ws + (size_t)S * 8;      // S*16 floats = 33.8 MB
    size_t needed = (size_t)S * 96;
    bool f32path = ws_size >= needed;

    hipMemsetAsync(voxb, 0, (size_t)S * 32, stream);
    scatter_kernel<<<(BN + 255) / 256, 256, 0, stream>>>(xyzp, feat, voxb, BN, logN);
    if (f32path) {
        repack_kernel<<<(S + 255) / 256, 256, 0, stream>>>(voxb, voxn, S);
        gather_kernel<true><<<BN / (WAVES * PPW), 256, 0, stream>>>(
            xyzp, voxn, voxb, W, bias, out, logN);
    } else {
        gather_kernel<false><<<BN / (WAVES * PPW), 256, 0, stream>>>(
            xyzp, voxn, voxb, W, bias, out, logN);
    }
}

// Round 4
// 172.392 us; speedup vs baseline: 3.7949x; 1.5123x over previous
//
#include <hip/hip_runtime.h>

#define HD 257
#define WD 257
#define NK 9
#define COUT 64

typedef unsigned int uint;
typedef short short8 __attribute__((ext_vector_type(8)));
typedef float f32x4 __attribute__((ext_vector_type(4)));

// f32 -> bf16 RNE
__device__ __forceinline__ uint pack_bf16(float a, float b) {
    uint ua = __float_as_uint(a), ub = __float_as_uint(b);
    ua += 0x7fffu + ((ua >> 16) & 1u);
    ub += 0x7fffu + ((ub >> 16) & 1u);
    return (ua >> 16) | (ub & 0xffff0000u);
}
__device__ __forceinline__ unsigned short bf16_1(float a) {
    uint ua = __float_as_uint(a);
    ua += 0x7fffu + ((ua >> 16) & 1u);
    return (unsigned short)(ua >> 16);
}

// packed 2xbf16 atomic add, device scope (cross-XCD coherent)
__device__ __forceinline__ void atomic_pk_add_bf16(uint* addr, uint val) {
    asm volatile("global_atomic_pk_add_bf16 %0, %1, off sc1"
                 :: "v"(addr), "v"(val) : "memory");
}

__global__ void scatter_kernel(const float* __restrict__ xyzp,
                               const float* __restrict__ feat,
                               uint* __restrict__ voxb,  // [S][8] packed bf16 sums
                               int BN, int logN) {
    int p = blockIdx.x * blockDim.x + threadIdx.x;
    if (p >= BN) return;
    int b = p >> logN;
    float4 v = reinterpret_cast<const float4*>(xyzp)[p];
    int y = (int)fminf(fmaxf(rintf(v.y * 256.0f), 0.0f), 256.0f);
    int x = (int)fminf(fmaxf(rintf(v.x * 256.0f), 0.0f), 256.0f);
    uint* dst = voxb + (size_t)((b * HD + y) * WD + x) * 8;
    const float2* f2 = reinterpret_cast<const float2*>(feat + (size_t)p * 14);
    float2 f0 = f2[0], f1 = f2[1], f2v = f2[2], f3 = f2[3];
    float2 f4 = f2[4], f5 = f2[5], f6 = f2[6];
    atomic_pk_add_bf16(dst + 0, pack_bf16(v.w, 1.0f - v.w));
    atomic_pk_add_bf16(dst + 1, pack_bf16(f0.x, f0.y));
    atomic_pk_add_bf16(dst + 2, pack_bf16(f1.x, f1.y));
    atomic_pk_add_bf16(dst + 3, pack_bf16(f2v.x, f2v.y));
    atomic_pk_add_bf16(dst + 4, pack_bf16(f3.x, f3.y));
    atomic_pk_add_bf16(dst + 5, pack_bf16(f4.x, f4.y));
    atomic_pk_add_bf16(dst + 6, pack_bf16(f5.x, f5.y));
    atomic_pk_add_bf16(dst + 7, pack_bf16(f6.x, f6.y));
}

// bf16 sums -> normalized bf16 means (count = ch0+ch1: each point adds p + (1-p))
__global__ void repack_kernel(const uint* __restrict__ vin,
                              uint* __restrict__ vout, int S) {
    int c = blockIdx.x * blockDim.x + threadIdx.x;
    if (c >= S) return;
    const uint4* rp = reinterpret_cast<const uint4*>(vin) + (size_t)c * 2;
    uint4 a = rp[0], b = rp[1];
    uint d[8] = {a.x, a.y, a.z, a.w, b.x, b.y, b.z, b.w};
    float f[16];
#pragma unroll
    for (int j = 0; j < 8; ++j) {
        f[2 * j]     = __uint_as_float(d[j] << 16);
        f[2 * j + 1] = __uint_as_float(d[j] & 0xffff0000u);
    }
    float inv = __builtin_amdgcn_rcpf(fmaxf(f[0] + f[1], 1.0f));
    uint o[8];
#pragma unroll
    for (int j = 0; j < 8; ++j)
        o[j] = pack_bf16(f[2 * j] * inv, f[2 * j + 1] * inv);
    uint4* op = reinterpret_cast<uint4*>(vout) + (size_t)c * 2;
    op[0] = make_uint4(o[0], o[1], o[2], o[3]);
    op[1] = make_uint4(o[4], o[5], o[6], o[7]);
}

// Per block (128 thr, 2 waves): 32 points. A[32][K=160] bf16 in LDS (row 336 B),
// wave w computes cols w*32..w*32+31. K-map: k = kn*16 + c, kn = dy*3+dx (ref order).
__global__ __launch_bounds__(128) void gather_mfma_kernel(
    const float* __restrict__ xyzp,
    const uint* __restrict__ voxn,   // [S][8] normalized bf16 pairs
    const float* __restrict__ W,     // [9][16][64] f32 = [144][64]
    const float* __restrict__ bias,
    float* __restrict__ out, int logN) {
    __shared__ __align__(16) char sA[32 * 336];

    const int tid = threadIdx.x;
    const int lane = tid & 63;
    const int w = tid >> 6;
    const int p0 = blockIdx.x * 32;
    const int hi = lane >> 4;   // 0..3
    const int lo = lane & 15;

    // ---- B fragments in registers: frag[s][n], k = s*32 + hi*8 + j (same map as A)
    short8 bfrag[5][2];
    float bv[2];
#pragma unroll
    for (int n = 0; n < 2; ++n) {
        int col = w * 32 + n * 16 + lo;
        bv[n] = bias[col];
#pragma unroll
        for (int s = 0; s < 5; ++s) {
            int kbase = s * 32 + hi * 8;
            short8 f;
#pragma unroll
            for (int j = 0; j < 8; ++j) {
                int k = kbase + j;
                float wv = 0.0f;
                if (k < 144) wv = W[(size_t)k * 64 + col];  // guard: no OOB read
                f[j] = (short)bf16_1(wv);
            }
            bfrag[s][n] = f;
        }
    }

    // ---- A build: per point, 3 contiguous 96 B spans (dy = -1,0,1); 16 B chunks.
    // chunk: i = idx/18, r = idx%18, seg = r/6 (dy+1), h = r%6 (kx = h>>1, half = h&1)
    for (int idx = tid; idx < 576; idx += 128) {
        int i = idx / 18;
        int r = idx - i * 18;
        int seg = r / 6;
        int h = r - seg * 6;
        float4 v = reinterpret_cast<const float4*>(xyzp)[p0 + i];
        int y = (int)fminf(fmaxf(rintf(v.y * 256.0f), 0.0f), 256.0f);
        int x = (int)fminf(fmaxf(rintf(v.x * 256.0f), 0.0f), 256.0f);
        int b = (p0 + i) >> logN;
        int ny = y + seg - 1;
        int kx = h >> 1;
        int nx = x - 1 + kx;
        uint4 val = make_uint4(0, 0, 0, 0);
        if ((uint)ny <= 256u && (uint)nx <= 256u) {
            size_t cell = (size_t)(b * HD + ny) * WD + nx;
            val = *reinterpret_cast<const uint4*>(
                reinterpret_cast<const char*>(voxn) + cell * 32 + (size_t)(h & 1) * 16);
        }
        *reinterpret_cast<uint4*>(sA + i * 336 + (seg * 3 + kx) * 32 + (h & 1) * 16) = val;
    }
    // zero pad k in [144,160)
    if (tid < 64) {
        int i = tid >> 1, h = tid & 1;
        *reinterpret_cast<uint4*>(sA + i * 336 + 288 + h * 16) = make_uint4(0, 0, 0, 0);
    }
    __syncthreads();

    // ---- MFMA: 2 M-tiles x 2 N-tiles x 5 K-steps
    f32x4 acc[2][2];
#pragma unroll
    for (int mt = 0; mt < 2; ++mt)
#pragma unroll
        for (int n = 0; n < 2; ++n)
            acc[mt][n] = (f32x4){bv[n], bv[n], bv[n], bv[n]};

#pragma unroll
    for (int mt = 0; mt < 2; ++mt) {
        const char* abase = sA + (mt * 16 + lo) * 336 + hi * 16;
#pragma unroll
        for (int s = 0; s < 5; ++s) {
            short8 a = *reinterpret_cast<const short8*>(abase + s * 64);
            acc[mt][0] = __builtin_amdgcn_mfma_f32_16x16x32_bf16(a, bfrag[s][0], acc[mt][0], 0, 0, 0);
            acc[mt][1] = __builtin_amdgcn_mfma_f32_16x16x32_bf16(a, bfrag[s][1], acc[mt][1], 0, 0, 0);
        }
    }

    // ---- store: D col = lane&15, row = hi*4 + reg (m89-verified)
#pragma unroll
    for (int mt = 0; mt < 2; ++mt)
#pragma unroll
        for (int n = 0; n < 2; ++n)
#pragma unroll
            for (int r = 0; r < 4; ++r) {
                int row = mt * 16 + hi * 4 + r;
                out[(size_t)(p0 + row) * 64 + w * 32 + n * 16 + lo] = acc[mt][n][r];
            }
}

extern "C" void kernel_launch(void* const* d_in, const int* in_sizes, int n_in,
                              void* d_out, int out_size, void* d_ws, size_t ws_size,
                              hipStream_t stream) {
    const float* xyzp = (const float*)d_in[0];
    const float* feat = (const float*)d_in[1];
    const float* W    = (const float*)d_in[2];
    const float* bias = (const float*)d_in[3];
    float* out = (float*)d_out;

    const int BN = in_sizes[0] / 4;  // 262144
    const int B = 8;
    const int N = BN / B;
    int logN = 0;
    while ((1 << logN) < N) ++logN;  // 15

    const int S = B * HD * WD;                 // 528392
    uint* voxb = (uint*)d_ws;                  // [S][8] bf16 sums: 16.9 MB
    uint* voxn = voxb + (size_t)S * 8;         // [S][8] bf16 means: 16.9 MB (33.8 total)
    (void)ws_size;

    hipMemsetAsync(voxb, 0, (size_t)S * 32, stream);
    scatter_kernel<<<(BN + 255) / 256, 256, 0, stream>>>(xyzp, feat, voxb, BN, logN);
    repack_kernel<<<(S + 255) / 256, 256, 0, stream>>>(voxb, voxn, S);
    gather_mfma_kernel<<<BN / 32, 128, 0, stream>>>(xyzp, voxn, W, bias, out, logN);
}

// Round 5
// 117.941 us; speedup vs baseline: 5.5470x; 1.4617x over previous
//
#include <hip/hip_runtime.h>

#define HD 257
#define WD 257
#define NB (8 * HD)   // 2056 (b,y)-row buckets
#define CAP 384       // max points per row bucket (lambda~128, 22 sigma headroom)
#define COUT 64
#define LROW 17       // LDS row stride (floats) per cell: breaks x*16 bank pattern

typedef unsigned int uint;
typedef unsigned short ushort;
typedef short short8 __attribute__((ext_vector_type(8)));
typedef float f32x4 __attribute__((ext_vector_type(4)));

// f32 -> bf16 RNE
__device__ __forceinline__ uint pack_bf16(float a, float b) {
    uint ua = __float_as_uint(a), ub = __float_as_uint(b);
    ua += 0x7fffu + ((ua >> 16) & 1u);
    ub += 0x7fffu + ((ub >> 16) & 1u);
    return (ua >> 16) | (ub & 0xffff0000u);
}
__device__ __forceinline__ unsigned short bf16_1(float a) {
    uint ua = __float_as_uint(a);
    ua += 0x7fffu + ((ua >> 16) & 1u);
    return (unsigned short)(ua >> 16);
}

// K1: bin points by (b,y) row. One u32 atomic per point + 32B payload + 2B x.
__global__ void bin_kernel(const float* __restrict__ xyzp,
                           const float* __restrict__ feat,
                           uint* __restrict__ cnt,      // [NB]
                           uint* __restrict__ payload,  // [NB][CAP][8] bf16 pairs
                           ushort* __restrict__ xpos,   // [NB][CAP]
                           int BN, int logN) {
    int p = blockIdx.x * blockDim.x + threadIdx.x;
    if (p >= BN) return;
    float4 v = reinterpret_cast<const float4*>(xyzp)[p];
    int y = (int)fminf(fmaxf(rintf(v.y * 256.0f), 0.0f), 256.0f);
    int x = (int)fminf(fmaxf(rintf(v.x * 256.0f), 0.0f), 256.0f);
    int b = p >> logN;
    int bucket = b * HD + y;
    uint slot = atomicAdd(&cnt[bucket], 1u);   // device-scope (default)
    if (slot >= CAP) return;                   // statistically impossible
    const float2* f2 = reinterpret_cast<const float2*>(feat + (size_t)p * 14);
    float2 f0 = f2[0], f1 = f2[1], f2v = f2[2], f3 = f2[3];
    float2 f4 = f2[4], f5 = f2[5], f6 = f2[6];
    size_t base = (size_t)bucket * CAP + slot;
    uint4* dst = reinterpret_cast<uint4*>(payload + base * 8);
    dst[0] = make_uint4(pack_bf16(v.w, 1.0f - v.w), pack_bf16(f0.x, f0.y),
                        pack_bf16(f1.x, f1.y), pack_bf16(f2v.x, f2v.y));
    dst[1] = make_uint4(pack_bf16(f3.x, f3.y), pack_bf16(f4.x, f4.y),
                        pack_bf16(f5.x, f5.y), pack_bf16(f6.x, f6.y));
    xpos[base] = (ushort)x;
}

// K2: one block per row bucket: LDS f32 accumulate, normalize, emit bf16 row.
__global__ __launch_bounds__(256) void accum_kernel(
    const uint* __restrict__ cnt,
    const uint* __restrict__ payload,
    const ushort* __restrict__ xpos,
    uint* __restrict__ voxn) {     // [S][8] normalized bf16 pairs
    __shared__ float l[WD * LROW];  // 17.5 KB
    int bucket = blockIdx.x;
    int tid = threadIdx.x;
    for (int i = tid; i < WD * LROW; i += 256) l[i] = 0.0f;
    __syncthreads();
    uint n = min(cnt[bucket], (uint)CAP);
    for (uint s = tid; s < n; s += 256) {
        size_t base = (size_t)bucket * CAP + s;
        const uint4* pp = reinterpret_cast<const uint4*>(payload + base * 8);
        uint4 a = pp[0], bq = pp[1];
        int x = xpos[base];
        float* cell = l + x * LROW;
        uint d[8] = {a.x, a.y, a.z, a.w, bq.x, bq.y, bq.z, bq.w};
#pragma unroll
        for (int j = 0; j < 8; ++j) {
            atomicAdd(&cell[2 * j],     __uint_as_float(d[j] << 16));
            atomicAdd(&cell[2 * j + 1], __uint_as_float(d[j] & 0xffff0000u));
        }
    }
    __syncthreads();
    for (int x = tid; x < WD; x += 256) {
        const float* c = l + x * LROW;
        float inv = __builtin_amdgcn_rcpf(fmaxf(c[0] + c[1], 1.0f));
        uint o[8];
#pragma unroll
        for (int j = 0; j < 8; ++j)
            o[j] = pack_bf16(c[2 * j] * inv, c[2 * j + 1] * inv);
        uint4* op = reinterpret_cast<uint4*>(voxn + ((size_t)bucket * WD + x) * 8);
        op[0] = make_uint4(o[0], o[1], o[2], o[3]);
        op[1] = make_uint4(o[4], o[5], o[6], o[7]);
    }
}

// K3: per block (128 thr, 2 waves): 32 points. A[32][K=160] bf16 in LDS (336 B row),
// wave w computes cols w*32..w*32+31. K-map: k = kn*16 + c, kn = dy*3+dx.
__global__ __launch_bounds__(128) void gather_mfma_kernel(
    const float* __restrict__ xyzp,
    const uint* __restrict__ voxn,   // [S][8] normalized bf16 pairs
    const float* __restrict__ W,     // [9][16][64] f32 = [144][64]
    const float* __restrict__ bias,
    float* __restrict__ out, int logN) {
    __shared__ __align__(16) char sA[32 * 336];

    const int tid = threadIdx.x;
    const int lane = tid & 63;
    const int w = tid >> 6;
    const int p0 = blockIdx.x * 32;
    const int hi = lane >> 4;
    const int lo = lane & 15;

    // B fragments: frag[s][n], k = s*32 + hi*8 + j (same k-map as A)
    short8 bfrag[5][2];
    float bv[2];
#pragma unroll
    for (int n = 0; n < 2; ++n) {
        int col = w * 32 + n * 16 + lo;
        bv[n] = bias[col];
#pragma unroll
        for (int s = 0; s < 5; ++s) {
            int kbase = s * 32 + hi * 8;
            short8 f;
#pragma unroll
            for (int j = 0; j < 8; ++j) {
                int k = kbase + j;
                float wv = 0.0f;
                if (k < 144) wv = W[(size_t)k * 64 + col];
                f[j] = (short)bf16_1(wv);
            }
            bfrag[s][n] = f;
        }
    }

    // A build: per point, 3 contiguous 96 B spans (dy=-1,0,1), 16 B chunks.
    for (int idx = tid; idx < 576; idx += 128) {
        int i = idx / 18;
        int r = idx - i * 18;
        int seg = r / 6;
        int h = r - seg * 6;
        float4 v = reinterpret_cast<const float4*>(xyzp)[p0 + i];
        int y = (int)fminf(fmaxf(rintf(v.y * 256.0f), 0.0f), 256.0f);
        int x = (int)fminf(fmaxf(rintf(v.x * 256.0f), 0.0f), 256.0f);
        int b = (p0 + i) >> logN;
        int ny = y + seg - 1;
        int kx = h >> 1;
        int nx = x - 1 + kx;
        uint4 val = make_uint4(0, 0, 0, 0);
        if ((uint)ny <= 256u && (uint)nx <= 256u) {
            size_t cell = (size_t)(b * HD + ny) * WD + nx;
            val = *reinterpret_cast<const uint4*>(
                reinterpret_cast<const char*>(voxn) + cell * 32 + (size_t)(h & 1) * 16);
        }
        *reinterpret_cast<uint4*>(sA + i * 336 + (seg * 3 + kx) * 32 + (h & 1) * 16) = val;
    }
    if (tid < 64) {  // zero-pad k in [144,160)
        int i = tid >> 1, h = tid & 1;
        *reinterpret_cast<uint4*>(sA + i * 336 + 288 + h * 16) = make_uint4(0, 0, 0, 0);
    }
    __syncthreads();

    f32x4 acc[2][2];
#pragma unroll
    for (int mt = 0; mt < 2; ++mt)
#pragma unroll
        for (int n = 0; n < 2; ++n)
            acc[mt][n] = (f32x4){bv[n], bv[n], bv[n], bv[n]};

#pragma unroll
    for (int mt = 0; mt < 2; ++mt) {
        const char* abase = sA + (mt * 16 + lo) * 336 + hi * 16;
#pragma unroll
        for (int s = 0; s < 5; ++s) {
            short8 a = *reinterpret_cast<const short8*>(abase + s * 64);
            acc[mt][0] = __builtin_amdgcn_mfma_f32_16x16x32_bf16(a, bfrag[s][0], acc[mt][0], 0, 0, 0);
            acc[mt][1] = __builtin_amdgcn_mfma_f32_16x16x32_bf16(a, bfrag[s][1], acc[mt][1], 0, 0, 0);
        }
    }

    // store: D col = lane&15, row = hi*4 + reg (m89-verified)
#pragma unroll
    for (int mt = 0; mt < 2; ++mt)
#pragma unroll
        for (int n = 0; n < 2; ++n)
#pragma unroll
            for (int r = 0; r < 4; ++r) {
                int row = mt * 16 + hi * 4 + r;
                out[(size_t)(p0 + row) * 64 + w * 32 + n * 16 + lo] = acc[mt][n][r];
            }
}

extern "C" void kernel_launch(void* const* d_in, const int* in_sizes, int n_in,
                              void* d_out, int out_size, void* d_ws, size_t ws_size,
                              hipStream_t stream) {
    const float* xyzp = (const float*)d_in[0];
    const float* feat = (const float*)d_in[1];
    const float* W    = (const float*)d_in[2];
    const float* bias = (const float*)d_in[3];
    float* out = (float*)d_out;

    const int BN = in_sizes[0] / 4;  // 262144
    const int B = 8;
    const int N = BN / B;
    int logN = 0;
    while ((1 << logN) < N) ++logN;  // 15

    const int S = B * HD * WD;  // 528392

    // ws layout (16B-aligned): cnt | payload | xpos | voxn  == 43.8 MB total
    uint* cnt = (uint*)d_ws;                              // NB*4      = 8224 B
    uint* payload = cnt + NB;                             // NB*CAP*32 = 25.26 MB
    ushort* xpos = (ushort*)(payload + (size_t)NB * CAP * 8);  // NB*CAP*2 = 1.58 MB
    uint* voxn = (uint*)(xpos + (size_t)NB * CAP);        // S*32      = 16.9 MB
    (void)ws_size;

    hipMemsetAsync(cnt, 0, NB * sizeof(uint), stream);
    bin_kernel<<<(BN + 255) / 256, 256, 0, stream>>>(xyzp, feat, cnt, payload, xpos, BN, logN);
    accum_kernel<<<NB, 256, 0, stream>>>(cnt, payload, xpos, voxn);
    gather_mfma_kernel<<<BN / 32, 128, 0, stream>>>(xyzp, voxn, W, bias, out, logN);
}

// Round 6
// 101.120 us; speedup vs baseline: 6.4697x; 1.1663x over previous
//
#include <hip/hip_runtime.h>

#define HD 257
#define WD 257
#define NB (8 * HD)   // 2056 (b,y)-row buckets
#define CAP 384       // max points per row bucket (lambda~128, 22 sigma headroom)
#define COUT 64
#define LROW 17       // accum LDS row stride (floats): breaks x*16 bank pattern
#define GPTS 64       // gather: points per block

typedef unsigned int uint;
typedef unsigned short ushort;
typedef short short8 __attribute__((ext_vector_type(8)));
typedef float f32x4 __attribute__((ext_vector_type(4)));

// f32 -> bf16 RNE
__device__ __forceinline__ uint pack_bf16(float a, float b) {
    uint ua = __float_as_uint(a), ub = __float_as_uint(b);
    ua += 0x7fffu + ((ua >> 16) & 1u);
    ub += 0x7fffu + ((ub >> 16) & 1u);
    return (ua >> 16) | (ub & 0xffff0000u);
}
__device__ __forceinline__ unsigned short bf16_1(float a) {
    uint ua = __float_as_uint(a);
    ua += 0x7fffu + ((ua >> 16) & 1u);
    return (unsigned short)(ua >> 16);
}

// K1: bin points by (b,y) row. One u32 atomic per point + 32B payload + 2B x.
__global__ void bin_kernel(const float* __restrict__ xyzp,
                           const float* __restrict__ feat,
                           uint* __restrict__ cnt,      // [NB]
                           uint* __restrict__ payload,  // [NB][CAP][8] bf16 pairs
                           ushort* __restrict__ xpos,   // [NB][CAP]
                           int BN, int logN) {
    int p = blockIdx.x * blockDim.x + threadIdx.x;
    if (p >= BN) return;
    float4 v = reinterpret_cast<const float4*>(xyzp)[p];
    int y = (int)fminf(fmaxf(rintf(v.y * 256.0f), 0.0f), 256.0f);
    int x = (int)fminf(fmaxf(rintf(v.x * 256.0f), 0.0f), 256.0f);
    int b = p >> logN;
    int bucket = b * HD + y;
    uint slot = atomicAdd(&cnt[bucket], 1u);
    if (slot >= CAP) return;                   // statistically impossible
    const float2* f2 = reinterpret_cast<const float2*>(feat + (size_t)p * 14);
    float2 f0 = f2[0], f1 = f2[1], f2v = f2[2], f3 = f2[3];
    float2 f4 = f2[4], f5 = f2[5], f6 = f2[6];
    size_t base = (size_t)bucket * CAP + slot;
    uint4* dst = reinterpret_cast<uint4*>(payload + base * 8);
    dst[0] = make_uint4(pack_bf16(v.w, 1.0f - v.w), pack_bf16(f0.x, f0.y),
                        pack_bf16(f1.x, f1.y), pack_bf16(f2v.x, f2v.y));
    dst[1] = make_uint4(pack_bf16(f3.x, f3.y), pack_bf16(f4.x, f4.y),
                        pack_bf16(f5.x, f5.y), pack_bf16(f6.x, f6.y));
    xpos[base] = (ushort)x;
}

// K2: one block per row bucket: LDS f32 accumulate, normalize, emit bf16 row.
__global__ __launch_bounds__(256) void accum_kernel(
    const uint* __restrict__ cnt,
    const uint* __restrict__ payload,
    const ushort* __restrict__ xpos,
    uint* __restrict__ voxn) {     // [S][8] normalized bf16 pairs
    __shared__ float l[WD * LROW];  // 17.5 KB
    int bucket = blockIdx.x;
    int tid = threadIdx.x;
    for (int i = tid; i < WD * LROW; i += 256) l[i] = 0.0f;
    __syncthreads();
    uint n = min(cnt[bucket], (uint)CAP);
    for (uint s = tid; s < n; s += 256) {
        size_t base = (size_t)bucket * CAP + s;
        const uint4* pp = reinterpret_cast<const uint4*>(payload + base * 8);
        uint4 a = pp[0], bq = pp[1];
        int x = xpos[base];
        float* cell = l + x * LROW;
        uint d[8] = {a.x, a.y, a.z, a.w, bq.x, bq.y, bq.z, bq.w};
#pragma unroll
        for (int j = 0; j < 8; ++j) {
            atomicAdd(&cell[2 * j],     __uint_as_float(d[j] << 16));
            atomicAdd(&cell[2 * j + 1], __uint_as_float(d[j] & 0xffff0000u));
        }
    }
    __syncthreads();
    for (int x = tid; x < WD; x += 256) {
        const float* c = l + x * LROW;
        float inv = __builtin_amdgcn_rcpf(fmaxf(c[0] + c[1], 1.0f));
        uint o[8];
#pragma unroll
        for (int j = 0; j < 8; ++j)
            o[j] = pack_bf16(c[2 * j] * inv, c[2 * j + 1] * inv);
        uint4* op = reinterpret_cast<uint4*>(voxn + ((size_t)bucket * WD + x) * 8);
        op[0] = make_uint4(o[0], o[1], o[2], o[3]);
        op[1] = make_uint4(o[4], o[5], o[6], o[7]);
    }
}

// K3: 64 points / 256 thr (4 waves). A[64][K=160] bf16 in LDS (336 B row).
// Wave w computes cols w*16..w*16+15 over all 64 rows. k = (dy*3+dx)*16 + c.
__global__ __launch_bounds__(256) void gather_mfma_kernel(
    const float* __restrict__ xyzp,
    const uint* __restrict__ voxn,   // [S][8] normalized bf16 pairs
    const float* __restrict__ W,     // [9][16][64] f32 = [144][64]
    const float* __restrict__ bias,
    float* __restrict__ out, int logN) {
    __shared__ __align__(16) char sA[GPTS * 336];  // 21504 B
    __shared__ int sCell[GPTS];
    __shared__ uint sYX[GPTS];

    const int tid = threadIdx.x;
    const int lane = tid & 63;
    const int w = tid >> 6;
    const int p0 = blockIdx.x * GPTS;
    const int hi = lane >> 4;
    const int lo = lane & 15;

    // per-point data computed ONCE (threads 0..63)
    if (tid < GPTS) {
        float4 v = reinterpret_cast<const float4*>(xyzp)[p0 + tid];
        int y = (int)fminf(fmaxf(rintf(v.y * 256.0f), 0.0f), 256.0f);
        int x = (int)fminf(fmaxf(rintf(v.x * 256.0f), 0.0f), 256.0f);
        int b = (p0 + tid) >> logN;
        sCell[tid] = (b * HD + y) * WD + x;
        sYX[tid] = ((uint)y << 16) | (uint)x;
    }

    // B fragments (issued before barrier; latency overlaps)
    short8 bfrag[5];
    float bv = bias[w * 16 + lo];
#pragma unroll
    for (int s = 0; s < 5; ++s) {
        int kbase = s * 32 + hi * 8;
        short8 f;
#pragma unroll
        for (int j = 0; j < 8; ++j) {
            int k = kbase + j;
            float wv = (k < 144) ? W[(size_t)k * 64 + w * 16 + lo] : 0.0f;
            f[j] = (short)bf16_1(wv);
        }
        bfrag[s] = f;
    }
    __syncthreads();

    // A build: 18 chunks/point (3 dy-segs x 3 kx x 2 halves of 16 B)
    for (int idx = tid; idx < GPTS * 18; idx += 256) {
        int i = idx / 18;
        int r = idx - i * 18;
        int seg = r / 6;          // dy+1
        int h = r - seg * 6;
        int kx = h >> 1;
        int half = h & 1;
        uint yx = sYX[i];
        int y = (int)(yx >> 16), x = (int)(yx & 0xffffu);
        int ny = y + seg - 1, nx = x + kx - 1;
        uint4 val = make_uint4(0, 0, 0, 0);
        if ((uint)ny <= 256u && (uint)nx <= 256u) {
            size_t ncell = (size_t)sCell[i] + (size_t)((seg - 1) * WD + (kx - 1));
            val = *reinterpret_cast<const uint4*>(
                reinterpret_cast<const char*>(voxn) + ncell * 32 + (size_t)half * 16);
        }
        *reinterpret_cast<uint4*>(sA + i * 336 + (seg * 3 + kx) * 32 + half * 16) = val;
    }
    // zero-pad k in [144,160)
    if (tid < GPTS * 2) {
        int i = tid >> 1, h = tid & 1;
        *reinterpret_cast<uint4*>(sA + i * 336 + 288 + h * 16) = make_uint4(0, 0, 0, 0);
    }
    __syncthreads();

    f32x4 acc[4];
#pragma unroll
    for (int mt = 0; mt < 4; ++mt) acc[mt] = (f32x4){bv, bv, bv, bv};

#pragma unroll
    for (int mt = 0; mt < 4; ++mt) {
        const char* abase = sA + (mt * 16 + lo) * 336 + hi * 16;
#pragma unroll
        for (int s = 0; s < 5; ++s) {
            short8 a = *reinterpret_cast<const short8*>(abase + s * 64);
            acc[mt] = __builtin_amdgcn_mfma_f32_16x16x32_bf16(a, bfrag[s], acc[mt], 0, 0, 0);
        }
    }

    // store: D col = lane&15, row = hi*4 + reg (m89-verified)
#pragma unroll
    for (int mt = 0; mt < 4; ++mt)
#pragma unroll
        for (int r = 0; r < 4; ++r) {
            int row = mt * 16 + hi * 4 + r;
            out[(size_t)(p0 + row) * 64 + w * 16 + lo] = acc[mt][r];
        }
}

extern "C" void kernel_launch(void* const* d_in, const int* in_sizes, int n_in,
                              void* d_out, int out_size, void* d_ws, size_t ws_size,
                              hipStream_t stream) {
    const float* xyzp = (const float*)d_in[0];
    const float* feat = (const float*)d_in[1];
    const float* W    = (const float*)d_in[2];
    const float* bias = (const float*)d_in[3];
    float* out = (float*)d_out;

    const int BN = in_sizes[0] / 4;  // 262144
    const int B = 8;
    const int N = BN / B;
    int logN = 0;
    while ((1 << logN) < N) ++logN;  // 15

    const int S = B * HD * WD;  // 528392

    // ws layout: cnt | payload | xpos | voxn == 43.8 MB total
    uint* cnt = (uint*)d_ws;                                   // 8224 B
    uint* payload = cnt + NB;                                  // 25.26 MB
    ushort* xpos = (ushort*)(payload + (size_t)NB * CAP * 8);  // 1.58 MB
    uint* voxn = (uint*)(xpos + (size_t)NB * CAP);             // 16.9 MB
    (void)ws_size;

    hipMemsetAsync(cnt, 0, NB * sizeof(uint), stream);
    bin_kernel<<<(BN + 255) / 256, 256, 0, stream>>>(xyzp, feat, cnt, payload, xpos, BN, logN);
    accum_kernel<<<NB, 256, 0, stream>>>(cnt, payload, xpos, voxn);
    gather_mfma_kernel<<<BN / GPTS, 256, 0, stream>>>(xyzp, voxn, W, bias, out, logN);
}

// Round 7
// 99.584 us; speedup vs baseline: 6.5695x; 1.0154x over previous
//
#include <hip/hip_runtime.h>

#define HD 257
#define WD 257
#define NB (8 * HD)   // 2056 (b,y)-row buckets
#define CAP 384       // max points per row bucket (lambda~128, 22 sigma headroom)
#define COUT 64
#define LROW 17       // accum LDS row stride (floats): breaks x*16 bank pattern
#define GPTS 64       // gather: points per block

typedef unsigned int uint;
typedef unsigned short ushort;
typedef short short8 __attribute__((ext_vector_type(8)));
typedef float f32x4 __attribute__((ext_vector_type(4)));

// f32 -> bf16 RNE
__device__ __forceinline__ uint pack_bf16(float a, float b) {
    uint ua = __float_as_uint(a), ub = __float_as_uint(b);
    ua += 0x7fffu + ((ua >> 16) & 1u);
    ub += 0x7fffu + ((ub >> 16) & 1u);
    return (ua >> 16) | (ub & 0xffff0000u);
}
__device__ __forceinline__ unsigned short bf16_1(float a) {
    uint ua = __float_as_uint(a);
    ua += 0x7fffu + ((ua >> 16) & 1u);
    return (unsigned short)(ua >> 16);
}

// K0: zero the 2056 row counters (hipMemsetAsync's fill kernel cost 42 us!)
__global__ void zero_cnt_kernel(uint* __restrict__ cnt) {
    int i = blockIdx.x * blockDim.x + threadIdx.x;
    if (i < NB) cnt[i] = 0u;
}

// K1: bin points by (b,y) row. One u32 atomic per point + 32B payload + 2B x.
__global__ void bin_kernel(const float* __restrict__ xyzp,
                           const float* __restrict__ feat,
                           uint* __restrict__ cnt,      // [NB]
                           uint* __restrict__ payload,  // [NB][CAP][8] bf16 pairs
                           ushort* __restrict__ xpos,   // [NB][CAP]
                           int BN, int logN) {
    int p = blockIdx.x * blockDim.x + threadIdx.x;
    if (p >= BN) return;
    float4 v = reinterpret_cast<const float4*>(xyzp)[p];
    int y = (int)fminf(fmaxf(rintf(v.y * 256.0f), 0.0f), 256.0f);
    int x = (int)fminf(fmaxf(rintf(v.x * 256.0f), 0.0f), 256.0f);
    int b = p >> logN;
    int bucket = b * HD + y;
    uint slot = atomicAdd(&cnt[bucket], 1u);
    if (slot >= CAP) return;                   // statistically impossible
    const float2* f2 = reinterpret_cast<const float2*>(feat + (size_t)p * 14);
    float2 f0 = f2[0], f1 = f2[1], f2v = f2[2], f3 = f2[3];
    float2 f4 = f2[4], f5 = f2[5], f6 = f2[6];
    size_t base = (size_t)bucket * CAP + slot;
    uint4* dst = reinterpret_cast<uint4*>(payload + base * 8);
    dst[0] = make_uint4(pack_bf16(v.w, 1.0f - v.w), pack_bf16(f0.x, f0.y),
                        pack_bf16(f1.x, f1.y), pack_bf16(f2v.x, f2v.y));
    dst[1] = make_uint4(pack_bf16(f3.x, f3.y), pack_bf16(f4.x, f4.y),
                        pack_bf16(f5.x, f5.y), pack_bf16(f6.x, f6.y));
    xpos[base] = (ushort)x;
}

// K2: one block per row bucket: LDS f32 accumulate, normalize, emit bf16 row.
__global__ __launch_bounds__(256) void accum_kernel(
    const uint* __restrict__ cnt,
    const uint* __restrict__ payload,
    const ushort* __restrict__ xpos,
    uint* __restrict__ voxn) {     // [S][8] normalized bf16 pairs
    __shared__ float l[WD * LROW];  // 17.5 KB
    int bucket = blockIdx.x;
    int tid = threadIdx.x;
    for (int i = tid; i < WD * LROW; i += 256) l[i] = 0.0f;
    __syncthreads();
    uint n = min(cnt[bucket], (uint)CAP);
    for (uint s = tid; s < n; s += 256) {
        size_t base = (size_t)bucket * CAP + s;
        const uint4* pp = reinterpret_cast<const uint4*>(payload + base * 8);
        uint4 a = pp[0], bq = pp[1];
        int x = xpos[base];
        float* cell = l + x * LROW;
        uint d[8] = {a.x, a.y, a.z, a.w, bq.x, bq.y, bq.z, bq.w};
#pragma unroll
        for (int j = 0; j < 8; ++j) {
            atomicAdd(&cell[2 * j],     __uint_as_float(d[j] << 16));
            atomicAdd(&cell[2 * j + 1], __uint_as_float(d[j] & 0xffff0000u));
        }
    }
    __syncthreads();
    for (int x = tid; x < WD; x += 256) {
        const float* c = l + x * LROW;
        float inv = __builtin_amdgcn_rcpf(fmaxf(c[0] + c[1], 1.0f));
        uint o[8];
#pragma unroll
        for (int j = 0; j < 8; ++j)
            o[j] = pack_bf16(c[2 * j] * inv, c[2 * j + 1] * inv);
        uint4* op = reinterpret_cast<uint4*>(voxn + ((size_t)bucket * WD + x) * 8);
        op[0] = make_uint4(o[0], o[1], o[2], o[3]);
        op[1] = make_uint4(o[4], o[5], o[6], o[7]);
    }
}

// K3: 64 points / 256 thr (4 waves). A[64][K=160] bf16 in LDS (336 B row).
// Wave w computes cols w*16..w*16+15 over all 64 rows. k = (dy*3+dx)*16 + c.
__global__ __launch_bounds__(256) void gather_mfma_kernel(
    const float* __restrict__ xyzp,
    const uint* __restrict__ voxn,   // [S][8] normalized bf16 pairs
    const float* __restrict__ W,     // [9][16][64] f32 = [144][64]
    const float* __restrict__ bias,
    float* __restrict__ out, int logN) {
    __shared__ __align__(16) char sA[GPTS * 336];  // 21504 B
    __shared__ int sCell[GPTS];
    __shared__ uint sYX[GPTS];

    const int tid = threadIdx.x;
    const int lane = tid & 63;
    const int w = tid >> 6;
    const int p0 = blockIdx.x * GPTS;
    const int hi = lane >> 4;
    const int lo = lane & 15;

    // per-point data computed ONCE (threads 0..63)
    if (tid < GPTS) {
        float4 v = reinterpret_cast<const float4*>(xyzp)[p0 + tid];
        int y = (int)fminf(fmaxf(rintf(v.y * 256.0f), 0.0f), 256.0f);
        int x = (int)fminf(fmaxf(rintf(v.x * 256.0f), 0.0f), 256.0f);
        int b = (p0 + tid) >> logN;
        sCell[tid] = (b * HD + y) * WD + x;
        sYX[tid] = ((uint)y << 16) | (uint)x;
    }

    // B fragments (issued before barrier; latency overlaps)
    short8 bfrag[5];
    float bv = bias[w * 16 + lo];
#pragma unroll
    for (int s = 0; s < 5; ++s) {
        int kbase = s * 32 + hi * 8;
        short8 f;
#pragma unroll
        for (int j = 0; j < 8; ++j) {
            int k = kbase + j;
            float wv = (k < 144) ? W[(size_t)k * 64 + w * 16 + lo] : 0.0f;
            f[j] = (short)bf16_1(wv);
        }
        bfrag[s] = f;
    }
    __syncthreads();

    // A build: 18 chunks/point (3 dy-segs x 3 kx x 2 halves of 16 B)
    for (int idx = tid; idx < GPTS * 18; idx += 256) {
        int i = idx / 18;
        int r = idx - i * 18;
        int seg = r / 6;          // dy+1
        int h = r - seg * 6;
        int kx = h >> 1;
        int half = h & 1;
        uint yx = sYX[i];
        int y = (int)(yx >> 16), x = (int)(yx & 0xffffu);
        int ny = y + seg - 1, nx = x + kx - 1;
        uint4 val = make_uint4(0, 0, 0, 0);
        if ((uint)ny <= 256u && (uint)nx <= 256u) {
            size_t ncell = (size_t)sCell[i] + (size_t)((seg - 1) * WD + (kx - 1));
            val = *reinterpret_cast<const uint4*>(
                reinterpret_cast<const char*>(voxn) + ncell * 32 + (size_t)half * 16);
        }
        *reinterpret_cast<uint4*>(sA + i * 336 + (seg * 3 + kx) * 32 + half * 16) = val;
    }
    // zero-pad k in [144,160)
    if (tid < GPTS * 2) {
        int i = tid >> 1, h = tid & 1;
        *reinterpret_cast<uint4*>(sA + i * 336 + 288 + h * 16) = make_uint4(0, 0, 0, 0);
    }
    __syncthreads();

    f32x4 acc[4];
#pragma unroll
    for (int mt = 0; mt < 4; ++mt) acc[mt] = (f32x4){bv, bv, bv, bv};

#pragma unroll
    for (int mt = 0; mt < 4; ++mt) {
        const char* abase = sA + (mt * 16 + lo) * 336 + hi * 16;
#pragma unroll
        for (int s = 0; s < 5; ++s) {
            short8 a = *reinterpret_cast<const short8*>(abase + s * 64);
            acc[mt] = __builtin_amdgcn_mfma_f32_16x16x32_bf16(a, bfrag[s], acc[mt], 0, 0, 0);
        }
    }

    // store: D col = lane&15, row = hi*4 + reg (m89-verified)
#pragma unroll
    for (int mt = 0; mt < 4; ++mt)
#pragma unroll
        for (int r = 0; r < 4; ++r) {
            int row = mt * 16 + hi * 4 + r;
            out[(size_t)(p0 + row) * 64 + w * 16 + lo] = acc[mt][r];
        }
}

extern "C" void kernel_launch(void* const* d_in, const int* in_sizes, int n_in,
                              void* d_out, int out_size, void* d_ws, size_t ws_size,
                              hipStream_t stream) {
    const float* xyzp = (const float*)d_in[0];
    const float* feat = (const float*)d_in[1];
    const float* W    = (const float*)d_in[2];
    const float* bias = (const float*)d_in[3];
    float* out = (float*)d_out;

    const int BN = in_sizes[0] / 4;  // 262144
    const int B = 8;
    const int N = BN / B;
    int logN = 0;
    while ((1 << logN) < N) ++logN;  // 15

    const int S = B * HD * WD;  // 528392

    // ws layout: cnt | payload | xpos | voxn == 43.8 MB total
    uint* cnt = (uint*)d_ws;                                   // 8224 B
    uint* payload = cnt + NB;                                  // 25.26 MB
    ushort* xpos = (ushort*)(payload + (size_t)NB * CAP * 8);  // 1.58 MB
    uint* voxn = (uint*)(xpos + (size_t)NB * CAP);             // 16.9 MB
    (void)ws_size;

    zero_cnt_kernel<<<(NB + 255) / 256, 256, 0, stream>>>(cnt);
    bin_kernel<<<(BN + 255) / 256, 256, 0, stream>>>(xyzp, feat, cnt, payload, xpos, BN, logN);
    accum_kernel<<<NB, 256, 0, stream>>>(cnt, payload, xpos, voxn);
    gather_mfma_kernel<<<BN / GPTS, 256, 0, stream>>>(xyzp, voxn, W, bias, out, logN);
}

// Round 8
// 96.863 us; speedup vs baseline: 6.7540x; 1.0281x over previous
//
#include <hip/hip_runtime.h>

#define HD 257
#define WD 257
#define NB (8 * HD)   // 2056 (b,y)-row buckets
#define CAP 384       // max points per row bucket (lambda~128, 22 sigma headroom)
#define COUT 64
#define LROW 17       // accum LDS row stride (floats): breaks x*16 bank pattern
#define RPB 2         // accum: rows per block
#define GPTS 64       // gather: points per block

typedef unsigned int uint;
typedef unsigned short ushort;
typedef short short8 __attribute__((ext_vector_type(8)));
typedef float f32x4 __attribute__((ext_vector_type(4)));

// f32 -> bf16 RNE
__device__ __forceinline__ uint pack_bf16(float a, float b) {
    uint ua = __float_as_uint(a), ub = __float_as_uint(b);
    ua += 0x7fffu + ((ua >> 16) & 1u);
    ub += 0x7fffu + ((ub >> 16) & 1u);
    return (ua >> 16) | (ub & 0xffff0000u);
}
__device__ __forceinline__ unsigned short bf16_1(float a) {
    uint ua = __float_as_uint(a);
    ua += 0x7fffu + ((ua >> 16) & 1u);
    return (unsigned short)(ua >> 16);
}

// K0: zero the 2056 row counters (dedicated kernel: memset fill costs a dispatch)
__global__ void zero_cnt_kernel(uint* __restrict__ cnt) {
    int i = blockIdx.x * blockDim.x + threadIdx.x;
    if (i < NB) cnt[i] = 0u;
}

// K1: bin-lite — per point: 1 atomic + 2B local-index write. No feat read, no payload.
__global__ void bin_kernel(const float* __restrict__ xyzp,
                           uint* __restrict__ cnt,      // [NB]
                           ushort* __restrict__ pidx,   // [NB][CAP] local point idx
                           int BN, int logN) {
    int p = blockIdx.x * blockDim.x + threadIdx.x;
    if (p >= BN) return;
    float4 v = reinterpret_cast<const float4*>(xyzp)[p];
    int y = (int)fminf(fmaxf(rintf(v.y * 256.0f), 0.0f), 256.0f);
    int b = p >> logN;
    int bucket = b * HD + y;
    uint slot = atomicAdd(&cnt[bucket], 1u);
    if (slot < CAP)
        pidx[(size_t)bucket * CAP + slot] = (ushort)(p - (b << logN));
}

// K2: accum-v2 — RPB rows/block; fetch point data directly, f32 LDS accumulate,
// normalize (count = ch0+ch1), emit bf16 voxel rows.
__global__ __launch_bounds__(256) void accum_kernel(
    const uint* __restrict__ cnt,
    const ushort* __restrict__ pidx,
    const float* __restrict__ xyzp,
    const float* __restrict__ feat,
    uint* __restrict__ voxn,       // [S][8] normalized bf16 pairs
    int logN) {
    __shared__ float l[RPB * WD * LROW];  // 2*4369*4 = 34952 B -> 4 blocks/CU
    const int tid = threadIdx.x;
    const int bucket0 = blockIdx.x * RPB;
    for (int i = tid; i < RPB * WD * LROW; i += 256) l[i] = 0.0f;
    __syncthreads();

    uint n0 = min(cnt[bucket0], (uint)CAP);
    uint n1 = min(cnt[bucket0 + 1], (uint)CAP);
    uint ntot = n0 + n1;
    for (uint s = tid; s < ntot; s += 256) {
        int r = (s >= n0) ? 1 : 0;
        uint slot = s - (r ? n0 : 0u);
        int bucket = bucket0 + r;
        int b = bucket / HD;              // const-div -> magic mul
        uint lp = pidx[(size_t)bucket * CAP + slot];
        int p = (b << logN) + (int)lp;
        float4 v = reinterpret_cast<const float4*>(xyzp)[p];
        int x = (int)fminf(fmaxf(rintf(v.x * 256.0f), 0.0f), 256.0f);
        float* cell = l + (r * WD + x) * LROW;
        atomicAdd(&cell[0], v.w);
        atomicAdd(&cell[1], 1.0f - v.w);
        const float2* f2 = reinterpret_cast<const float2*>(feat + (size_t)p * 14);
#pragma unroll
        for (int j = 0; j < 7; ++j) {
            float2 fv = f2[j];
            atomicAdd(&cell[2 + 2 * j], fv.x);
            atomicAdd(&cell[3 + 2 * j], fv.y);
        }
    }
    __syncthreads();

    for (int i = tid; i < RPB * WD; i += 256) {
        int r = i / WD;
        int x = i - r * WD;
        const float* c = l + (r * WD + x) * LROW;
        float inv = __builtin_amdgcn_rcpf(fmaxf(c[0] + c[1], 1.0f));
        uint o[8];
#pragma unroll
        for (int j = 0; j < 8; ++j)
            o[j] = pack_bf16(c[2 * j] * inv, c[2 * j + 1] * inv);
        uint4* op = reinterpret_cast<uint4*>(voxn + ((size_t)(bucket0 + r) * WD + x) * 8);
        op[0] = make_uint4(o[0], o[1], o[2], o[3]);
        op[1] = make_uint4(o[4], o[5], o[6], o[7]);
    }
}

// K3: 64 points / 256 thr (4 waves). A[64][K=160] bf16 in LDS (336 B row).
// Wave w computes cols w*16..w*16+15 over all 64 rows. k = (dy*3+dx)*16 + c.
__global__ __launch_bounds__(256) void gather_mfma_kernel(
    const float* __restrict__ xyzp,
    const uint* __restrict__ voxn,   // [S][8] normalized bf16 pairs
    const float* __restrict__ W,     // [9][16][64] f32 = [144][64]
    const float* __restrict__ bias,
    float* __restrict__ out, int logN) {
    __shared__ __align__(16) char sA[GPTS * 336];  // 21504 B
    __shared__ int sCell[GPTS];
    __shared__ uint sYX[GPTS];

    const int tid = threadIdx.x;
    const int lane = tid & 63;
    const int w = tid >> 6;
    const int p0 = blockIdx.x * GPTS;
    const int hi = lane >> 4;
    const int lo = lane & 15;

    // per-point data computed ONCE (threads 0..63)
    if (tid < GPTS) {
        float4 v = reinterpret_cast<const float4*>(xyzp)[p0 + tid];
        int y = (int)fminf(fmaxf(rintf(v.y * 256.0f), 0.0f), 256.0f);
        int x = (int)fminf(fmaxf(rintf(v.x * 256.0f), 0.0f), 256.0f);
        int b = (p0 + tid) >> logN;
        sCell[tid] = (b * HD + y) * WD + x;
        sYX[tid] = ((uint)y << 16) | (uint)x;
    }

    // B fragments (issued before barrier; latency overlaps)
    short8 bfrag[5];
    float bv = bias[w * 16 + lo];
#pragma unroll
    for (int s = 0; s < 5; ++s) {
        int kbase = s * 32 + hi * 8;
        short8 f;
#pragma unroll
        for (int j = 0; j < 8; ++j) {
            int k = kbase + j;
            float wv = (k < 144) ? W[(size_t)k * 64 + w * 16 + lo] : 0.0f;
            f[j] = (short)bf16_1(wv);
        }
        bfrag[s] = f;
    }
    __syncthreads();

    // A build: 18 chunks/point (3 dy-segs x 3 kx x 2 halves of 16 B)
    for (int idx = tid; idx < GPTS * 18; idx += 256) {
        int i = idx / 18;
        int r = idx - i * 18;
        int seg = r / 6;          // dy+1
        int h = r - seg * 6;
        int kx = h >> 1;
        int half = h & 1;
        uint yx = sYX[i];
        int y = (int)(yx >> 16), x = (int)(yx & 0xffffu);
        int ny = y + seg - 1, nx = x + kx - 1;
        uint4 val = make_uint4(0, 0, 0, 0);
        if ((uint)ny <= 256u && (uint)nx <= 256u) {
            size_t ncell = (size_t)sCell[i] + (size_t)((seg - 1) * WD + (kx - 1));
            val = *reinterpret_cast<const uint4*>(
                reinterpret_cast<const char*>(voxn) + ncell * 32 + (size_t)half * 16);
        }
        *reinterpret_cast<uint4*>(sA + i * 336 + (seg * 3 + kx) * 32 + half * 16) = val;
    }
    // zero-pad k in [144,160)
    if (tid < GPTS * 2) {
        int i = tid >> 1, h = tid & 1;
        *reinterpret_cast<uint4*>(sA + i * 336 + 288 + h * 16) = make_uint4(0, 0, 0, 0);
    }
    __syncthreads();

    f32x4 acc[4];
#pragma unroll
    for (int mt = 0; mt < 4; ++mt) acc[mt] = (f32x4){bv, bv, bv, bv};

#pragma unroll
    for (int mt = 0; mt < 4; ++mt) {
        const char* abase = sA + (mt * 16 + lo) * 336 + hi * 16;
#pragma unroll
        for (int s = 0; s < 5; ++s) {
            short8 a = *reinterpret_cast<const short8*>(abase + s * 64);
            acc[mt] = __builtin_amdgcn_mfma_f32_16x16x32_bf16(a, bfrag[s], acc[mt], 0, 0, 0);
        }
    }

    // store: D col = lane&15, row = hi*4 + reg (m89-verified)
#pragma unroll
    for (int mt = 0; mt < 4; ++mt)
#pragma unroll
        for (int r = 0; r < 4; ++r) {
            int row = mt * 16 + hi * 4 + r;
            out[(size_t)(p0 + row) * 64 + w * 16 + lo] = acc[mt][r];
        }
}

extern "C" void kernel_launch(void* const* d_in, const int* in_sizes, int n_in,
                              void* d_out, int out_size, void* d_ws, size_t ws_size,
                              hipStream_t stream) {
    const float* xyzp = (const float*)d_in[0];
    const float* feat = (const float*)d_in[1];
    const float* W    = (const float*)d_in[2];
    const float* bias = (const float*)d_in[3];
    float* out = (float*)d_out;

    const int BN = in_sizes[0] / 4;  // 262144
    const int B = 8;
    const int N = BN / B;
    int logN = 0;
    while ((1 << logN) < N) ++logN;  // 15

    const int S = B * HD * WD;  // 528392

    // ws layout: cnt | pidx | voxn == 18.5 MB total
    uint* cnt = (uint*)d_ws;                               // 8224 B
    ushort* pidx = (ushort*)(cnt + NB);                    // NB*CAP*2 = 1.58 MB
    uint* voxn = (uint*)(pidx + (size_t)NB * CAP);         // S*32 = 16.9 MB
    (void)ws_size;

    zero_cnt_kernel<<<(NB + 255) / 256, 256, 0, stream>>>(cnt);
    bin_kernel<<<(BN + 255) / 256, 256, 0, stream>>>(xyzp, cnt, pidx, BN, logN);
    accum_kernel<<<NB / RPB, 256, 0, stream>>>(cnt, pidx, xyzp, feat, voxn, logN);
    gather_mfma_kernel<<<BN / GPTS, 256, 0, stream>>>(xyzp, voxn, W, bias, out, logN);
}